// Round 1
// baseline (5435.097 us; speedup 1.0000x reference)
//
#include <hip/hip_runtime.h>

#define N_COL 100000
#define N_CON 20000
#define HDIM 128

// ---------- tiny transpose: dst[c*R+r] = src[r*C+c] ----------
__global__ void transpose_k(const float* __restrict__ src, float* __restrict__ dst, int R, int C) {
    int idx = blockIdx.x * blockDim.x + threadIdx.x;
    if (idx < R * C) {
        int r = idx / C, c = idx - r * C;
        dst[c * R + r] = src[idx];
    }
}

// ---------- encoder: out[n,h] = relu(sum_k x[n,k]*WT[k,h] + b[h]) ----------
template <int D>
__global__ __launch_bounds__(256) void encoder_k(const float* __restrict__ x,
                                                 const float* __restrict__ WT,
                                                 const float* __restrict__ b,
                                                 float* __restrict__ out, int N) {
    int idx = blockIdx.x * blockDim.x + threadIdx.x;
    if (idx >= N * HDIM) return;
    int n = idx >> 7, h = idx & 127;
    const float* xr = x + (size_t)n * D;
    float acc = b[h];
#pragma unroll
    for (int k = 0; k < D; k++) acc = fmaf(xr[k], WT[k * HDIM + h], acc);
    out[idx] = fmaxf(acc, 0.f);
}

// ---------- degree counts (float, for the mean) ----------
__global__ void degree_k(const int* __restrict__ ecol, const int* __restrict__ econ,
                         float* deg_col, float* deg_con, int E) {
    int e = blockIdx.x * blockDim.x + threadIdx.x;
    if (e < E) {
        atomicAdd(&deg_col[ecol[e]], 1.f);
        atomicAdd(&deg_con[econ[e]], 1.f);
    }
}

// ---------- scatter-add: agg[dst] += tab[src], 32 threads x float4 per edge ----------
__global__ __launch_bounds__(256) void scatter_k(const float* __restrict__ tab,
                                                 const int* __restrict__ sidx,
                                                 const int* __restrict__ didx,
                                                 float* __restrict__ agg, int E) {
    long long t = (long long)blockIdx.x * blockDim.x + threadIdx.x;
    int e = (int)(t >> 5);
    if (e >= E) return;
    int q = (int)(t & 31) * 4;
    int s = sidx[e], d = didx[e];
    float4 v = *reinterpret_cast<const float4*>(tab + (size_t)s * HDIM + q);
    float* p = agg + (size_t)d * HDIM + q;
    atomicAdd(p + 0, v.x);
    atomicAdd(p + 1, v.y);
    atomicAdd(p + 2, v.z);
    atomicAdd(p + 3, v.w);
}

// ---------- fused SAGE post: out[n,h] = relu(inv_deg[n]*(agg[n,:]@WlT[:,h]) + bl[h] + x[n,:]@WrT[:,h]) ----------
// block = 256 threads: h = t&127, g = t>>7; 8 nodes per g-group, 16 nodes per block.
__global__ __launch_bounds__(256) void sage_post_k(const float* __restrict__ agg,
                                                   const float* __restrict__ deg,
                                                   const float* __restrict__ xdst,
                                                   const float* __restrict__ WlT,
                                                   const float* __restrict__ bl,
                                                   const float* __restrict__ WrT,
                                                   float* __restrict__ out, int N) {
    int t = threadIdx.x;
    int h = t & 127, g = t >> 7;
    int n0 = blockIdx.x * 16 + g * 8;
    float accA[8] = {0.f, 0.f, 0.f, 0.f, 0.f, 0.f, 0.f, 0.f};
    float accX[8] = {0.f, 0.f, 0.f, 0.f, 0.f, 0.f, 0.f, 0.f};
    for (int k4 = 0; k4 < HDIM / 4; ++k4) {
        float4 a4[8], x4[8];
#pragma unroll
        for (int i = 0; i < 8; i++) {
            a4[i] = *reinterpret_cast<const float4*>(agg + (size_t)(n0 + i) * HDIM + k4 * 4);
            x4[i] = *reinterpret_cast<const float4*>(xdst + (size_t)(n0 + i) * HDIM + k4 * 4);
        }
#pragma unroll
        for (int kk = 0; kk < 4; kk++) {
            int k = k4 * 4 + kk;
            float wl = WlT[k * HDIM + h];
            float wr = WrT[k * HDIM + h];
#pragma unroll
            for (int i = 0; i < 8; i++) {
                float av = kk == 0 ? a4[i].x : kk == 1 ? a4[i].y : kk == 2 ? a4[i].z : a4[i].w;
                float xv = kk == 0 ? x4[i].x : kk == 1 ? x4[i].y : kk == 2 ? x4[i].z : x4[i].w;
                accA[i] = fmaf(av, wl, accA[i]);
                accX[i] = fmaf(xv, wr, accX[i]);
            }
        }
    }
    float bb = bl[h];
#pragma unroll
    for (int i = 0; i < 8; i++) {
        float inv = 1.f / fmaxf(deg[n0 + i], 1.f);
        out[(size_t)(n0 + i) * HDIM + h] = fmaxf(fmaf(accA[i], inv, accX[i] + bb), 0.f);
    }
}

// ---------- Q-head: out[n] = relu(h2[n,:]@W1T + b1) @ W2 + b2 ; one wave per node ----------
__global__ __launch_bounds__(256) void qhead_k(const float* __restrict__ h2,
                                               const float* __restrict__ W1T,
                                               const float* __restrict__ b1,
                                               const float* __restrict__ W2,
                                               const float* __restrict__ b2,
                                               float* __restrict__ out, int N) {
    int wid = threadIdx.x >> 6;
    int j = threadIdx.x & 63;
    int n = blockIdx.x * 4 + wid;
    if (n >= N) return;
    float acc = b1[j];
    const float* row = h2 + (size_t)n * HDIM;
    for (int k4 = 0; k4 < HDIM / 4; k4++) {
        float4 hv = *reinterpret_cast<const float4*>(row + k4 * 4);
        acc = fmaf(hv.x, W1T[(k4 * 4 + 0) * 64 + j], acc);
        acc = fmaf(hv.y, W1T[(k4 * 4 + 1) * 64 + j], acc);
        acc = fmaf(hv.z, W1T[(k4 * 4 + 2) * 64 + j], acc);
        acc = fmaf(hv.w, W1T[(k4 * 4 + 3) * 64 + j], acc);
    }
    float v = fmaxf(acc, 0.f) * W2[j];
#pragma unroll
    for (int off = 32; off > 0; off >>= 1) v += __shfl_down(v, off);
    if (j == 0) out[n] = v + b2[0];
}

extern "C" void kernel_launch(void* const* d_in, const int* in_sizes, int n_in,
                              void* d_out, int out_size, void* d_ws, size_t ws_size,
                              hipStream_t stream) {
    const float* x_col = (const float*)d_in[0];
    const float* x_con = (const float*)d_in[1];
    const int* edge_col = (const int*)d_in[2];
    const int* edge_con = (const int*)d_in[3];
    const float* W_col = (const float*)d_in[4];
    const float* b_col = (const float*)d_in[5];
    const float* W_con = (const float*)d_in[6];
    const float* b_con = (const float*)d_in[7];
    const float* c1_cn_Wl = (const float*)d_in[8];
    const float* c1_cn_bl = (const float*)d_in[9];
    const float* c1_cn_Wr = (const float*)d_in[10];
    const float* c1_nc_Wl = (const float*)d_in[11];
    const float* c1_nc_bl = (const float*)d_in[12];
    const float* c1_nc_Wr = (const float*)d_in[13];
    // d_in[14..16] = c2_cn_* : dead (h_con2 deleted in reference)
    const float* c2_nc_Wl = (const float*)d_in[17];
    const float* c2_nc_bl = (const float*)d_in[18];
    const float* c2_nc_Wr = (const float*)d_in[19];
    const float* q_W1 = (const float*)d_in[20];
    const float* q_b1 = (const float*)d_in[21];
    const float* q_W2 = (const float*)d_in[22];
    const float* q_b2 = (const float*)d_in[23];
    float* out = (float*)d_out;
    const int E = in_sizes[2];

    float* ws = (float*)d_ws;
    size_t o = 0;
    float* h_col = ws + o;   o += (size_t)N_COL * HDIM;
    float* h_con = ws + o;   o += (size_t)N_CON * HDIM;
    float* agg_con = ws + o; o += (size_t)N_CON * HDIM;
    float* n_con = ws + o;   o += (size_t)N_CON * HDIM;
    float* agg_col = ws + o; o += (size_t)N_COL * HDIM;
    float* n_col = ws + o;   o += (size_t)N_COL * HDIM;
    float* deg_col = ws + o; o += N_COL;
    float* deg_con = ws + o; o += N_CON;
    float* W_colT = ws + o;  o += 16 * HDIM;
    float* W_conT = ws + o;  o += 8 * HDIM;
    float* c1_cn_WlT = ws + o; o += HDIM * HDIM;
    float* c1_cn_WrT = ws + o; o += HDIM * HDIM;
    float* c1_nc_WlT = ws + o; o += HDIM * HDIM;
    float* c1_nc_WrT = ws + o; o += HDIM * HDIM;
    float* c2_nc_WlT = ws + o; o += HDIM * HDIM;
    float* c2_nc_WrT = ws + o; o += HDIM * HDIM;
    float* q_W1T = ws + o;     o += HDIM * 64;
    float* h_col2 = h_col;  // h_col dead after conv1_nc post -> reuse

    auto T = [&](const float* s, float* d, int R, int C) {
        transpose_k<<<(R * C + 255) / 256, 256, 0, stream>>>(s, d, R, C);
    };
    T(W_col, W_colT, HDIM, 16);
    T(W_con, W_conT, HDIM, 8);
    T(c1_cn_Wl, c1_cn_WlT, HDIM, HDIM);
    T(c1_cn_Wr, c1_cn_WrT, HDIM, HDIM);
    T(c1_nc_Wl, c1_nc_WlT, HDIM, HDIM);
    T(c1_nc_Wr, c1_nc_WrT, HDIM, HDIM);
    T(c2_nc_Wl, c2_nc_WlT, HDIM, HDIM);
    T(c2_nc_Wr, c2_nc_WrT, HDIM, HDIM);
    T(q_W1, q_W1T, 64, HDIM);

    encoder_k<16><<<((size_t)N_COL * HDIM + 255) / 256, 256, 0, stream>>>(x_col, W_colT, b_col, h_col, N_COL);
    encoder_k<8><<<((size_t)N_CON * HDIM + 255) / 256, 256, 0, stream>>>(x_con, W_conT, b_con, h_con, N_CON);

    // degrees (deg_col & deg_con contiguous -> one memset)
    hipMemsetAsync(deg_col, 0, (N_COL + N_CON) * sizeof(float), stream);
    degree_k<<<(E + 255) / 256, 256, 0, stream>>>(edge_col, edge_con, deg_col, deg_con, E);

    int sc_blocks = (int)(((long long)E * 32 + 255) / 256);

    // conv1 col->con
    hipMemsetAsync(agg_con, 0, (size_t)N_CON * HDIM * sizeof(float), stream);
    scatter_k<<<sc_blocks, 256, 0, stream>>>(h_col, edge_col, edge_con, agg_con, E);
    sage_post_k<<<N_CON / 16, 256, 0, stream>>>(agg_con, deg_con, h_con, c1_cn_WlT, c1_cn_bl, c1_cn_WrT, n_con, N_CON);

    // conv1 con->col
    hipMemsetAsync(agg_col, 0, (size_t)N_COL * HDIM * sizeof(float), stream);
    scatter_k<<<sc_blocks, 256, 0, stream>>>(h_con, edge_con, edge_col, agg_col, E);
    sage_post_k<<<N_COL / 16, 256, 0, stream>>>(agg_col, deg_col, h_col, c1_nc_WlT, c1_nc_bl, c1_nc_WrT, n_col, N_COL);

    // conv2 con->col (col->con branch is dead in the reference)
    hipMemsetAsync(agg_col, 0, (size_t)N_COL * HDIM * sizeof(float), stream);
    scatter_k<<<sc_blocks, 256, 0, stream>>>(n_con, edge_con, edge_col, agg_col, E);
    sage_post_k<<<N_COL / 16, 256, 0, stream>>>(agg_col, deg_col, n_col, c2_nc_WlT, c2_nc_bl, c2_nc_WrT, h_col2, N_COL);

    // Q-head
    qhead_k<<<N_COL / 4, 256, 0, stream>>>(h_col2, q_W1T, q_b1, q_W2, q_b2, out, N_COL);
}

// Round 2
// 1611.263 us; speedup vs baseline: 3.3732x; 3.3732x over previous
//
#include <hip/hip_runtime.h>

#define N_COL 100000
#define N_CON 20000
#define HDIM 128
#define SCAN_B 1024  // elements scanned per block (256 thr x 4)

// ---------- tiny transpose: dst[c*R+r] = src[r*C+c] ----------
__global__ void transpose_k(const float* __restrict__ src, float* __restrict__ dst, int R, int C) {
    int idx = blockIdx.x * blockDim.x + threadIdx.x;
    if (idx < R * C) {
        int r = idx / C, c = idx - r * C;
        dst[c * R + r] = src[idx];
    }
}

// ---------- encoder: out[n,h] = relu(sum_k x[n,k]*WT[k,h] + b[h]) ----------
template <int D>
__global__ __launch_bounds__(256) void encoder_k(const float* __restrict__ x,
                                                 const float* __restrict__ WT,
                                                 const float* __restrict__ b,
                                                 float* __restrict__ out, int N) {
    int idx = blockIdx.x * blockDim.x + threadIdx.x;
    if (idx >= N * HDIM) return;
    int n = idx >> 7, h = idx & 127;
    const float* xr = x + (size_t)n * D;
    float acc = b[h];
#pragma unroll
    for (int k = 0; k < D; k++) acc = fmaf(xr[k], WT[k * HDIM + h], acc);
    out[idx] = fmaxf(acc, 0.f);
}

// ---------- CSR build: counts ----------
__global__ void count_k(const int* __restrict__ ecol, const int* __restrict__ econ,
                        int* cnt_col, int* cnt_con, int E) {
    int e = blockIdx.x * blockDim.x + threadIdx.x;
    if (e < E) {
        atomicAdd(&cnt_col[ecol[e]], 1);
        atomicAdd(&cnt_con[econ[e]], 1);
    }
}

// ---------- 3-phase exclusive scan ----------
__global__ __launch_bounds__(256) void scan1_k(const int* __restrict__ cnt, int n,
                                               int* __restrict__ offs, int* __restrict__ partials) {
    __shared__ int lds[256];
    int t = threadIdx.x;
    int base = blockIdx.x * SCAN_B + t * 4;
    int v[4], s = 0;
#pragma unroll
    for (int i = 0; i < 4; i++) { int idx = base + i; v[i] = (idx < n) ? cnt[idx] : 0; s += v[i]; }
    lds[t] = s; __syncthreads();
    for (int off = 1; off < 256; off <<= 1) {
        int x = (t >= off) ? lds[t - off] : 0; __syncthreads();
        lds[t] += x; __syncthreads();
    }
    int excl = lds[t] - s;
    if (t == 255) partials[blockIdx.x] = lds[255];
    int run = excl;
#pragma unroll
    for (int i = 0; i < 4; i++) { int idx = base + i; if (idx < n) offs[idx] = run; run += v[i]; }
}

__global__ __launch_bounds__(256) void scan2_k(int* partials, int nb) {  // nb <= 256, single block
    __shared__ int lds[256];
    int t = threadIdx.x;
    int v = (t < nb) ? partials[t] : 0;
    lds[t] = v; __syncthreads();
    for (int off = 1; off < 256; off <<= 1) {
        int x = (t >= off) ? lds[t - off] : 0; __syncthreads();
        lds[t] += x; __syncthreads();
    }
    if (t < nb) partials[t] = lds[t] - v;  // exclusive
}

__global__ void scan3_k(int* offs, int n, const int* __restrict__ partials) {
    int i = blockIdx.x * blockDim.x + threadIdx.x;
    if (i < n) offs[i] += partials[i / SCAN_B];
}

// ---------- CSR fill: srclist bucketed by destination ----------
__global__ void fill_k(const int* __restrict__ sidx, const int* __restrict__ didx,
                       const int* __restrict__ offs, int* cursor, int* __restrict__ srclist, int E) {
    int e = blockIdx.x * blockDim.x + threadIdx.x;
    if (e < E) {
        int d = didx[e];
        int p = offs[d] + atomicAdd(&cursor[d], 1);
        srclist[p] = sidx[e];
    }
}

// ---------- gather segment-mean: one wave per dst node, lane owns 2 of 128 cols ----------
__global__ __launch_bounds__(256) void gather_mean_k(const float* __restrict__ tab,
                                                     const int* __restrict__ srclist,
                                                     const int* __restrict__ offs,
                                                     const int* __restrict__ cnt,
                                                     float* __restrict__ out, int N) {
    int wid = threadIdx.x >> 6, lane = threadIdx.x & 63;
    int n = blockIdx.x * 4 + wid;
    if (n >= N) return;
    int c = cnt[n], st = offs[n];
    const int* sl = srclist + st;
    float ax = 0.f, ay = 0.f;
    int j = 0;
    for (; j + 1 < c; j += 2) {
        int s0 = sl[j], s1 = sl[j + 1];
        float2 a = *reinterpret_cast<const float2*>(tab + (size_t)s0 * HDIM + lane * 2);
        float2 b = *reinterpret_cast<const float2*>(tab + (size_t)s1 * HDIM + lane * 2);
        ax += a.x + b.x; ay += a.y + b.y;
    }
    if (j < c) {
        int s0 = sl[j];
        float2 a = *reinterpret_cast<const float2*>(tab + (size_t)s0 * HDIM + lane * 2);
        ax += a.x; ay += a.y;
    }
    float inv = 1.f / fmaxf((float)c, 1.f);
    float2 r; r.x = ax * inv; r.y = ay * inv;
    *reinterpret_cast<float2*>(out + (size_t)n * HDIM + lane * 2) = r;
}

// ---------- fused SAGE post: out[n,h] = relu(mean[n,:]@WlT[:,h] + bl[h] + x[n,:]@WrT[:,h]) ----------
__global__ __launch_bounds__(256) void sage_post_k(const float* __restrict__ agg,
                                                   const float* __restrict__ xdst,
                                                   const float* __restrict__ WlT,
                                                   const float* __restrict__ bl,
                                                   const float* __restrict__ WrT,
                                                   float* __restrict__ out, int N) {
    int t = threadIdx.x;
    int h = t & 127, g = t >> 7;
    int n0 = blockIdx.x * 16 + g * 8;
    float accA[8] = {0.f}, accX[8] = {0.f};
    for (int k4 = 0; k4 < HDIM / 4; ++k4) {
        float4 a4[8], x4[8];
#pragma unroll
        for (int i = 0; i < 8; i++) {
            a4[i] = *reinterpret_cast<const float4*>(agg + (size_t)(n0 + i) * HDIM + k4 * 4);
            x4[i] = *reinterpret_cast<const float4*>(xdst + (size_t)(n0 + i) * HDIM + k4 * 4);
        }
#pragma unroll
        for (int kk = 0; kk < 4; kk++) {
            int k = k4 * 4 + kk;
            float wl = WlT[k * HDIM + h];
            float wr = WrT[k * HDIM + h];
#pragma unroll
            for (int i = 0; i < 8; i++) {
                float av = kk == 0 ? a4[i].x : kk == 1 ? a4[i].y : kk == 2 ? a4[i].z : a4[i].w;
                float xv = kk == 0 ? x4[i].x : kk == 1 ? x4[i].y : kk == 2 ? x4[i].z : x4[i].w;
                accA[i] = fmaf(av, wl, accA[i]);
                accX[i] = fmaf(xv, wr, accX[i]);
            }
        }
    }
    float bb = bl[h];
#pragma unroll
    for (int i = 0; i < 8; i++)
        out[(size_t)(n0 + i) * HDIM + h] = fmaxf(accA[i] + bb + accX[i], 0.f);
}

// ---------- Q-head: out[n] = relu(h2[n,:]@W1T + b1) @ W2 + b2 ; one wave per node ----------
__global__ __launch_bounds__(256) void qhead_k(const float* __restrict__ h2,
                                               const float* __restrict__ W1T,
                                               const float* __restrict__ b1,
                                               const float* __restrict__ W2,
                                               const float* __restrict__ b2,
                                               float* __restrict__ out, int N) {
    int wid = threadIdx.x >> 6;
    int j = threadIdx.x & 63;
    int n = blockIdx.x * 4 + wid;
    if (n >= N) return;
    float acc = b1[j];
    const float* row = h2 + (size_t)n * HDIM;
    for (int k4 = 0; k4 < HDIM / 4; k4++) {
        float4 hv = *reinterpret_cast<const float4*>(row + k4 * 4);
        acc = fmaf(hv.x, W1T[(k4 * 4 + 0) * 64 + j], acc);
        acc = fmaf(hv.y, W1T[(k4 * 4 + 1) * 64 + j], acc);
        acc = fmaf(hv.z, W1T[(k4 * 4 + 2) * 64 + j], acc);
        acc = fmaf(hv.w, W1T[(k4 * 4 + 3) * 64 + j], acc);
    }
    float v = fmaxf(acc, 0.f) * W2[j];
#pragma unroll
    for (int off = 32; off > 0; off >>= 1) v += __shfl_down(v, off);
    if (j == 0) out[n] = v + b2[0];
}

extern "C" void kernel_launch(void* const* d_in, const int* in_sizes, int n_in,
                              void* d_out, int out_size, void* d_ws, size_t ws_size,
                              hipStream_t stream) {
    const float* x_col = (const float*)d_in[0];
    const float* x_con = (const float*)d_in[1];
    const int* edge_col = (const int*)d_in[2];
    const int* edge_con = (const int*)d_in[3];
    const float* W_col = (const float*)d_in[4];
    const float* b_col = (const float*)d_in[5];
    const float* W_con = (const float*)d_in[6];
    const float* b_con = (const float*)d_in[7];
    const float* c1_cn_Wl = (const float*)d_in[8];
    const float* c1_cn_bl = (const float*)d_in[9];
    const float* c1_cn_Wr = (const float*)d_in[10];
    const float* c1_nc_Wl = (const float*)d_in[11];
    const float* c1_nc_bl = (const float*)d_in[12];
    const float* c1_nc_Wr = (const float*)d_in[13];
    // d_in[14..16] = c2_cn_* : dead (h_con2 deleted in reference)
    const float* c2_nc_Wl = (const float*)d_in[17];
    const float* c2_nc_bl = (const float*)d_in[18];
    const float* c2_nc_Wr = (const float*)d_in[19];
    const float* q_W1 = (const float*)d_in[20];
    const float* q_b1 = (const float*)d_in[21];
    const float* q_W2 = (const float*)d_in[22];
    const float* q_b2 = (const float*)d_in[23];
    float* out = (float*)d_out;
    const int E = in_sizes[2];

    float* ws = (float*)d_ws;
    size_t o = 0;
    float* h_col = ws + o;   o += (size_t)N_COL * HDIM;
    float* h_con = ws + o;   o += (size_t)N_CON * HDIM;
    float* agg_con = ws + o; o += (size_t)N_CON * HDIM;
    float* n_con = ws + o;   o += (size_t)N_CON * HDIM;
    float* agg_col = ws + o; o += (size_t)N_COL * HDIM;
    float* n_col = ws + o;   o += (size_t)N_COL * HDIM;
    float* W_colT = ws + o;  o += 16 * HDIM;
    float* W_conT = ws + o;  o += 8 * HDIM;
    float* c1_cn_WlT = ws + o; o += HDIM * HDIM;
    float* c1_cn_WrT = ws + o; o += HDIM * HDIM;
    float* c1_nc_WlT = ws + o; o += HDIM * HDIM;
    float* c1_nc_WrT = ws + o; o += HDIM * HDIM;
    float* c2_nc_WlT = ws + o; o += HDIM * HDIM;
    float* c2_nc_WrT = ws + o; o += HDIM * HDIM;
    float* q_W1T = ws + o;     o += HDIM * 64;
    // CSR scratch (int views)
    int* iws = (int*)(ws + o);
    size_t io = 0;
    int* cnt_col = iws + io;  io += N_COL;
    int* cnt_con = iws + io;  io += N_CON;
    int* offs_col = iws + io; io += N_COL;
    int* offs_con = iws + io; io += N_CON;
    int* cursor = iws + io;   io += N_COL;  // reused for both fills
    int* partials = iws + io; io += 256;
    int* srclist_col = iws + io; io += E;   // dst=col buckets, stores con src idx
    int* srclist_con = iws + io; io += E;   // dst=con buckets, stores col src idx
    float* h_col2 = h_col;  // h_col dead after conv1_nc post -> reuse

    auto T = [&](const float* s, float* d, int R, int C) {
        transpose_k<<<(R * C + 255) / 256, 256, 0, stream>>>(s, d, R, C);
    };
    T(W_col, W_colT, HDIM, 16);
    T(W_con, W_conT, HDIM, 8);
    T(c1_cn_Wl, c1_cn_WlT, HDIM, HDIM);
    T(c1_cn_Wr, c1_cn_WrT, HDIM, HDIM);
    T(c1_nc_Wl, c1_nc_WlT, HDIM, HDIM);
    T(c1_nc_Wr, c1_nc_WrT, HDIM, HDIM);
    T(c2_nc_Wl, c2_nc_WlT, HDIM, HDIM);
    T(c2_nc_Wr, c2_nc_WrT, HDIM, HDIM);
    T(q_W1, q_W1T, 64, HDIM);

    encoder_k<16><<<((size_t)N_COL * HDIM + 255) / 256, 256, 0, stream>>>(x_col, W_colT, b_col, h_col, N_COL);
    encoder_k<8><<<((size_t)N_CON * HDIM + 255) / 256, 256, 0, stream>>>(x_con, W_conT, b_con, h_con, N_CON);

    // ---- CSR build (both directions) ----
    hipMemsetAsync(cnt_col, 0, (N_COL + N_CON) * sizeof(int), stream);  // cnt_col+cnt_con contiguous
    count_k<<<(E + 255) / 256, 256, 0, stream>>>(edge_col, edge_con, cnt_col, cnt_con, E);

    int nb_col = (N_COL + SCAN_B - 1) / SCAN_B;  // 98
    int nb_con = (N_CON + SCAN_B - 1) / SCAN_B;  // 20
    scan1_k<<<nb_col, 256, 0, stream>>>(cnt_col, N_COL, offs_col, partials);
    scan2_k<<<1, 256, 0, stream>>>(partials, nb_col);
    scan3_k<<<(N_COL + 255) / 256, 256, 0, stream>>>(offs_col, N_COL, partials);
    scan1_k<<<nb_con, 256, 0, stream>>>(cnt_con, N_CON, offs_con, partials);
    scan2_k<<<1, 256, 0, stream>>>(partials, nb_con);
    scan3_k<<<(N_CON + 255) / 256, 256, 0, stream>>>(offs_con, N_CON, partials);

    hipMemsetAsync(cursor, 0, N_COL * sizeof(int), stream);
    fill_k<<<(E + 255) / 256, 256, 0, stream>>>(edge_con, edge_col, offs_col, cursor, srclist_col, E);
    hipMemsetAsync(cursor, 0, N_CON * sizeof(int), stream);
    fill_k<<<(E + 255) / 256, 256, 0, stream>>>(edge_col, edge_con, offs_con, cursor, srclist_con, E);

    // ---- conv1 col->con ----
    gather_mean_k<<<(N_CON + 3) / 4, 256, 0, stream>>>(h_col, srclist_con, offs_con, cnt_con, agg_con, N_CON);
    sage_post_k<<<N_CON / 16, 256, 0, stream>>>(agg_con, h_con, c1_cn_WlT, c1_cn_bl, c1_cn_WrT, n_con, N_CON);

    // ---- conv1 con->col ----
    gather_mean_k<<<(N_COL + 3) / 4, 256, 0, stream>>>(h_con, srclist_col, offs_col, cnt_col, agg_col, N_COL);
    sage_post_k<<<N_COL / 16, 256, 0, stream>>>(agg_col, h_col, c1_nc_WlT, c1_nc_bl, c1_nc_WrT, n_col, N_COL);

    // ---- conv2 con->col (col->con branch dead) ----
    gather_mean_k<<<(N_COL + 3) / 4, 256, 0, stream>>>(n_con, srclist_col, offs_col, cnt_col, agg_col, N_COL);
    sage_post_k<<<N_COL / 16, 256, 0, stream>>>(agg_col, n_col, c2_nc_WlT, c2_nc_bl, c2_nc_WrT, h_col2, N_COL);

    // ---- Q-head ----
    qhead_k<<<N_COL / 4, 256, 0, stream>>>(h_col2, q_W1T, q_b1, q_W2, q_b2, out, N_COL);
}

// Round 4
// 931.748 us; speedup vs baseline: 5.8332x; 1.7293x over previous
//
#include <hip/hip_runtime.h>

#define N_COL 100000
#define N_CON 20000
#define HDIM 128
#define SCAN_B 1024  // elements scanned per block (256 thr x 4)

// ---------- tiny transpose: dst[c*R+r] = src[r*C+c] ----------
__global__ void transpose_k(const float* __restrict__ src, float* __restrict__ dst, int R, int C) {
    int idx = blockIdx.x * blockDim.x + threadIdx.x;
    if (idx < R * C) {
        int r = idx / C, c = idx - r * C;
        dst[c * R + r] = src[idx];
    }
}

// ---------- encoder: out[n,h] = relu(sum_k x[n,k]*WT[k,h] + b[h]) ----------
template <int D>
__global__ __launch_bounds__(256) void encoder_k(const float* __restrict__ x,
                                                 const float* __restrict__ WT,
                                                 const float* __restrict__ b,
                                                 float* __restrict__ out, int N) {
    int idx = blockIdx.x * blockDim.x + threadIdx.x;
    if (idx >= N * HDIM) return;
    int n = idx >> 7, h = idx & 127;
    const float* xr = x + (size_t)n * D;
    float acc = b[h];
#pragma unroll
    for (int k = 0; k < D; k++) acc = fmaf(xr[k], WT[k * HDIM + h], acc);
    out[idx] = fmaxf(acc, 0.f);
}

// ---------- CSR build: counts ----------
__global__ void count_k(const int* __restrict__ ecol, const int* __restrict__ econ,
                        int* cnt_col, int* cnt_con, int E) {
    int e = blockIdx.x * blockDim.x + threadIdx.x;
    if (e < E) {
        atomicAdd(&cnt_col[ecol[e]], 1);
        atomicAdd(&cnt_con[econ[e]], 1);
    }
}

// ---------- 3-phase exclusive scan ----------
__global__ __launch_bounds__(256) void scan1_k(const int* __restrict__ cnt, int n,
                                               int* __restrict__ offs, int* __restrict__ partials) {
    __shared__ int lds[256];
    int t = threadIdx.x;
    int base = blockIdx.x * SCAN_B + t * 4;
    int v[4], s = 0;
#pragma unroll
    for (int i = 0; i < 4; i++) { int idx = base + i; v[i] = (idx < n) ? cnt[idx] : 0; s += v[i]; }
    lds[t] = s; __syncthreads();
    for (int off = 1; off < 256; off <<= 1) {
        int x = (t >= off) ? lds[t - off] : 0; __syncthreads();
        lds[t] += x; __syncthreads();
    }
    int excl = lds[t] - s;
    if (t == 255) partials[blockIdx.x] = lds[255];
    int run = excl;
#pragma unroll
    for (int i = 0; i < 4; i++) { int idx = base + i; if (idx < n) offs[idx] = run; run += v[i]; }
}

__global__ __launch_bounds__(256) void scan2_k(int* partials, int nb) {  // nb <= 256, single block
    __shared__ int lds[256];
    int t = threadIdx.x;
    int v = (t < nb) ? partials[t] : 0;
    lds[t] = v; __syncthreads();
    for (int off = 1; off < 256; off <<= 1) {
        int x = (t >= off) ? lds[t - off] : 0; __syncthreads();
        lds[t] += x; __syncthreads();
    }
    if (t < nb) partials[t] = lds[t] - v;  // exclusive
}

__global__ void scan3_k(int* offs, int n, const int* __restrict__ partials) {
    int i = blockIdx.x * blockDim.x + threadIdx.x;
    if (i < n) offs[i] += partials[i / SCAN_B];
}

// ---------- CSR fill: srclist bucketed by destination ----------
__global__ void fill_k(const int* __restrict__ sidx, const int* __restrict__ didx,
                       const int* __restrict__ offs, int* cursor, int* __restrict__ srclist, int E) {
    int e = blockIdx.x * blockDim.x + threadIdx.x;
    if (e < E) {
        int d = didx[e];
        int p = offs[d] + atomicAdd(&cursor[d], 1);
        srclist[p] = sidx[e];
    }
}

// ---------- gather segment-mean: one wave per dst node, lane owns 2 of 128 cols ----------
__global__ __launch_bounds__(256) void gather_mean_k(const float* __restrict__ tab,
                                                     const int* __restrict__ srclist,
                                                     const int* __restrict__ offs,
                                                     const int* __restrict__ cnt,
                                                     float* __restrict__ out, int N) {
    int wid = threadIdx.x >> 6, lane = threadIdx.x & 63;
    int n = blockIdx.x * 4 + wid;
    if (n >= N) return;
    int c = cnt[n], st = offs[n];
    const int* sl = srclist + st;
    float ax = 0.f, ay = 0.f;
    int j = 0;
    for (; j + 1 < c; j += 2) {
        int s0 = sl[j], s1 = sl[j + 1];
        float2 a = *reinterpret_cast<const float2*>(tab + (size_t)s0 * HDIM + lane * 2);
        float2 b = *reinterpret_cast<const float2*>(tab + (size_t)s1 * HDIM + lane * 2);
        ax += a.x + b.x; ay += a.y + b.y;
    }
    if (j < c) {
        int s0 = sl[j];
        float2 a = *reinterpret_cast<const float2*>(tab + (size_t)s0 * HDIM + lane * 2);
        ax += a.x; ay += a.y;
    }
    float inv = 1.f / fmaxf((float)c, 1.f);
    float2 r; r.x = ax * inv; r.y = ay * inv;
    *reinterpret_cast<float2*>(out + (size_t)n * HDIM + lane * 2) = r;
}

// ---------- SAGE post as LDS-tiled dual GEMM ----------
// out[n,h] = relu( agg[n,:]@WlT[:,h] + x[n,:]@WrT[:,h] + bl[h] ), i.e. [N,256]@[256,128].
// BM=64 rows/block, BN=128 (full), BK=16. 256 thr: tx=t&15 -> cols tx*8..+7, ty=t>>4 -> rows ty*4..+3.
__global__ __launch_bounds__(256) void sage_gemm_k(const float* __restrict__ agg,
                                                   const float* __restrict__ xdst,
                                                   const float* __restrict__ WlT,
                                                   const float* __restrict__ bl,
                                                   const float* __restrict__ WrT,
                                                   float* __restrict__ out, int N) {
    __shared__ float As[64][20];    // pad 16->20: float4-aligned, 2-way bank (free)
    __shared__ float Ws[16][128];
    int t = threadIdx.x;
    int tx = t & 15, ty = t >> 4;
    int n0 = blockIdx.x * 64;
    float acc[4][8];
#pragma unroll
    for (int i = 0; i < 4; i++)
#pragma unroll
        for (int j = 0; j < 8; j++) acc[i][j] = 0.f;

    // A-stage coords: each thread loads one float4
    int ar = t >> 2, akq = (t & 3) * 4;
    // W-stage coords: each thread loads 8 floats of one k-row
    int wk = t >> 4, wc = (t & 15) * 8;

    for (int kb = 0; kb < 16; ++kb) {
        const float* src = (kb < 8) ? agg : xdst;
        const float* W = (kb < 8) ? WlT : WrT;
        int k0 = (kb & 7) * 16;
        {
            int row = n0 + ar;
            float4 v = (row < N) ? *reinterpret_cast<const float4*>(src + (size_t)row * HDIM + k0 + akq)
                                 : make_float4(0.f, 0.f, 0.f, 0.f);
            *reinterpret_cast<float4*>(&As[ar][akq]) = v;
        }
        {
            const float* wp = W + (size_t)(k0 + wk) * HDIM + wc;
            *reinterpret_cast<float4*>(&Ws[wk][wc]) = *reinterpret_cast<const float4*>(wp);
            *reinterpret_cast<float4*>(&Ws[wk][wc + 4]) = *reinterpret_cast<const float4*>(wp + 4);
        }
        __syncthreads();
#pragma unroll
        for (int k = 0; k < 16; ++k) {
            float a[4];
#pragma unroll
            for (int i = 0; i < 4; i++) a[i] = As[ty * 4 + i][k];
            float4 w0 = *reinterpret_cast<const float4*>(&Ws[k][tx * 8]);
            float4 w1 = *reinterpret_cast<const float4*>(&Ws[k][tx * 8 + 4]);
            float w[8] = {w0.x, w0.y, w0.z, w0.w, w1.x, w1.y, w1.z, w1.w};
#pragma unroll
            for (int i = 0; i < 4; i++)
#pragma unroll
                for (int j = 0; j < 8; j++) acc[i][j] = fmaf(a[i], w[j], acc[i][j]);
        }
        __syncthreads();
    }
    // epilogue: bias + relu + store
    float4 b0 = *reinterpret_cast<const float4*>(bl + tx * 8);
    float4 b1 = *reinterpret_cast<const float4*>(bl + tx * 8 + 4);
    float bb[8] = {b0.x, b0.y, b0.z, b0.w, b1.x, b1.y, b1.z, b1.w};
#pragma unroll
    for (int i = 0; i < 4; i++) {
        int row = n0 + ty * 4 + i;
        if (row < N) {
            float4 r0, r1;
            r0.x = fmaxf(acc[i][0] + bb[0], 0.f);
            r0.y = fmaxf(acc[i][1] + bb[1], 0.f);
            r0.z = fmaxf(acc[i][2] + bb[2], 0.f);
            r0.w = fmaxf(acc[i][3] + bb[3], 0.f);
            r1.x = fmaxf(acc[i][4] + bb[4], 0.f);
            r1.y = fmaxf(acc[i][5] + bb[5], 0.f);
            r1.z = fmaxf(acc[i][6] + bb[6], 0.f);
            r1.w = fmaxf(acc[i][7] + bb[7], 0.f);
            float* op = out + (size_t)row * HDIM + tx * 8;
            *reinterpret_cast<float4*>(op) = r0;
            *reinterpret_cast<float4*>(op + 4) = r1;
        }
    }
}

// ---------- Q-head: out[n] = relu(h2[n,:]@W1T + b1) @ W2 + b2 ; one wave per node ----------
__global__ __launch_bounds__(256) void qhead_k(const float* __restrict__ h2,
                                               const float* __restrict__ W1T,
                                               const float* __restrict__ b1,
                                               const float* __restrict__ W2,
                                               const float* __restrict__ b2,
                                               float* __restrict__ out, int N) {
    int wid = threadIdx.x >> 6;
    int j = threadIdx.x & 63;
    int n = blockIdx.x * 4 + wid;
    if (n >= N) return;
    float acc = b1[j];
    const float* row = h2 + (size_t)n * HDIM;
    for (int k4 = 0; k4 < HDIM / 4; k4++) {
        float4 hv = *reinterpret_cast<const float4*>(row + k4 * 4);
        acc = fmaf(hv.x, W1T[(k4 * 4 + 0) * 64 + j], acc);
        acc = fmaf(hv.y, W1T[(k4 * 4 + 1) * 64 + j], acc);
        acc = fmaf(hv.z, W1T[(k4 * 4 + 2) * 64 + j], acc);
        acc = fmaf(hv.w, W1T[(k4 * 4 + 3) * 64 + j], acc);
    }
    float v = fmaxf(acc, 0.f) * W2[j];
#pragma unroll
    for (int off = 32; off > 0; off >>= 1) v += __shfl_down(v, off);
    if (j == 0) out[n] = v + b2[0];
}

extern "C" void kernel_launch(void* const* d_in, const int* in_sizes, int n_in,
                              void* d_out, int out_size, void* d_ws, size_t ws_size,
                              hipStream_t stream) {
    const float* x_col = (const float*)d_in[0];
    const float* x_con = (const float*)d_in[1];
    const int* edge_col = (const int*)d_in[2];
    const int* edge_con = (const int*)d_in[3];
    const float* W_col = (const float*)d_in[4];
    const float* b_col = (const float*)d_in[5];
    const float* W_con = (const float*)d_in[6];
    const float* b_con = (const float*)d_in[7];
    const float* c1_cn_Wl = (const float*)d_in[8];
    const float* c1_cn_bl = (const float*)d_in[9];
    const float* c1_cn_Wr = (const float*)d_in[10];
    const float* c1_nc_Wl = (const float*)d_in[11];
    const float* c1_nc_bl = (const float*)d_in[12];
    const float* c1_nc_Wr = (const float*)d_in[13];
    // d_in[14..16] = c2_cn_* : dead (h_con2 deleted in reference)
    const float* c2_nc_Wl = (const float*)d_in[17];
    const float* c2_nc_bl = (const float*)d_in[18];
    const float* c2_nc_Wr = (const float*)d_in[19];
    const float* q_W1 = (const float*)d_in[20];
    const float* q_b1 = (const float*)d_in[21];
    const float* q_W2 = (const float*)d_in[22];
    const float* q_b2 = (const float*)d_in[23];
    float* out = (float*)d_out;
    const int E = in_sizes[2];

    float* ws = (float*)d_ws;
    size_t o = 0;
    float* h_col = ws + o;   o += (size_t)N_COL * HDIM;
    float* h_con = ws + o;   o += (size_t)N_CON * HDIM;
    float* agg_con = ws + o; o += (size_t)N_CON * HDIM;
    float* n_con = ws + o;   o += (size_t)N_CON * HDIM;
    float* agg_col = ws + o; o += (size_t)N_COL * HDIM;
    float* n_col = ws + o;   o += (size_t)N_COL * HDIM;
    float* W_colT = ws + o;  o += 16 * HDIM;
    float* W_conT = ws + o;  o += 8 * HDIM;
    float* c1_cn_WlT = ws + o; o += HDIM * HDIM;
    float* c1_cn_WrT = ws + o; o += HDIM * HDIM;
    float* c1_nc_WlT = ws + o; o += HDIM * HDIM;
    float* c1_nc_WrT = ws + o; o += HDIM * HDIM;
    float* c2_nc_WlT = ws + o; o += HDIM * HDIM;
    float* c2_nc_WrT = ws + o; o += HDIM * HDIM;
    float* q_W1T = ws + o;     o += HDIM * 64;
    // CSR scratch (int views)
    int* iws = (int*)(ws + o);
    size_t io = 0;
    int* cnt_col = iws + io;  io += N_COL;
    int* cnt_con = iws + io;  io += N_CON;
    int* offs_col = iws + io; io += N_COL;
    int* offs_con = iws + io; io += N_CON;
    int* cursor = iws + io;   io += N_COL;  // reused for both fills
    int* partials = iws + io; io += 256;
    int* srclist_col = iws + io; io += E;   // dst=col buckets, stores con src idx
    int* srclist_con = iws + io; io += E;   // dst=con buckets, stores col src idx
    float* h_col2 = h_col;  // h_col dead after conv1_nc post -> reuse

    auto T = [&](const float* s, float* d, int R, int C) {
        transpose_k<<<(R * C + 255) / 256, 256, 0, stream>>>(s, d, R, C);
    };
    T(W_col, W_colT, HDIM, 16);
    T(W_con, W_conT, HDIM, 8);
    T(c1_cn_Wl, c1_cn_WlT, HDIM, HDIM);
    T(c1_cn_Wr, c1_cn_WrT, HDIM, HDIM);
    T(c1_nc_Wl, c1_nc_WlT, HDIM, HDIM);
    T(c1_nc_Wr, c1_nc_WrT, HDIM, HDIM);
    T(c2_nc_Wl, c2_nc_WlT, HDIM, HDIM);
    T(c2_nc_Wr, c2_nc_WrT, HDIM, HDIM);
    T(q_W1, q_W1T, 64, HDIM);

    encoder_k<16><<<((size_t)N_COL * HDIM + 255) / 256, 256, 0, stream>>>(x_col, W_colT, b_col, h_col, N_COL);
    encoder_k<8><<<((size_t)N_CON * HDIM + 255) / 256, 256, 0, stream>>>(x_con, W_conT, b_con, h_con, N_CON);

    // ---- CSR build (both directions) ----
    hipMemsetAsync(cnt_col, 0, (N_COL + N_CON) * sizeof(int), stream);  // cnt_col+cnt_con contiguous
    count_k<<<(E + 255) / 256, 256, 0, stream>>>(edge_col, edge_con, cnt_col, cnt_con, E);

    int nb_col = (N_COL + SCAN_B - 1) / SCAN_B;  // 98
    int nb_con = (N_CON + SCAN_B - 1) / SCAN_B;  // 20
    scan1_k<<<nb_col, 256, 0, stream>>>(cnt_col, N_COL, offs_col, partials);
    scan2_k<<<1, 256, 0, stream>>>(partials, nb_col);
    scan3_k<<<(N_COL + 255) / 256, 256, 0, stream>>>(offs_col, N_COL, partials);
    scan1_k<<<nb_con, 256, 0, stream>>>(cnt_con, N_CON, offs_con, partials);
    scan2_k<<<1, 256, 0, stream>>>(partials, nb_con);
    scan3_k<<<(N_CON + 255) / 256, 256, 0, stream>>>(offs_con, N_CON, partials);

    hipMemsetAsync(cursor, 0, N_COL * sizeof(int), stream);
    fill_k<<<(E + 255) / 256, 256, 0, stream>>>(edge_con, edge_col, offs_col, cursor, srclist_col, E);
    hipMemsetAsync(cursor, 0, N_CON * sizeof(int), stream);
    fill_k<<<(E + 255) / 256, 256, 0, stream>>>(edge_col, edge_con, offs_con, cursor, srclist_con, E);

    // ---- conv1 col->con ----
    gather_mean_k<<<(N_CON + 3) / 4, 256, 0, stream>>>(h_col, srclist_con, offs_con, cnt_con, agg_con, N_CON);
    sage_gemm_k<<<(N_CON + 63) / 64, 256, 0, stream>>>(agg_con, h_con, c1_cn_WlT, c1_cn_bl, c1_cn_WrT, n_con, N_CON);

    // ---- conv1 con->col ----
    gather_mean_k<<<(N_COL + 3) / 4, 256, 0, stream>>>(h_con, srclist_col, offs_col, cnt_col, agg_col, N_COL);
    sage_gemm_k<<<(N_COL + 63) / 64, 256, 0, stream>>>(agg_col, h_col, c1_nc_WlT, c1_nc_bl, c1_nc_WrT, n_col, N_COL);

    // ---- conv2 con->col (col->con branch dead) ----
    gather_mean_k<<<(N_COL + 3) / 4, 256, 0, stream>>>(n_con, srclist_col, offs_col, cnt_col, agg_col, N_COL);
    sage_gemm_k<<<(N_COL + 63) / 64, 256, 0, stream>>>(agg_col, n_col, c2_nc_WlT, c2_nc_bl, c2_nc_WrT, h_col2, N_COL);

    // ---- Q-head ----
    qhead_k<<<N_COL / 4, 256, 0, stream>>>(h_col2, q_W1T, q_b1, q_W2, q_b2, out, N_COL);
}

// Round 5
// 831.794 us; speedup vs baseline: 6.5342x; 1.1202x over previous
//
#include <hip/hip_runtime.h>

#define N_COL 100000
#define N_CON 20000
#define HDIM 128
#define SCAN_B 1024  // elements scanned per block (256 thr x 4)

// ---------- tiny transpose: dst[c*R+r] = src[r*C+c] ----------
__global__ void transpose_k(const float* __restrict__ src, float* __restrict__ dst, int R, int C) {
    int idx = blockIdx.x * blockDim.x + threadIdx.x;
    if (idx < R * C) {
        int r = idx / C, c = idx - r * C;
        dst[c * R + r] = src[idx];
    }
}

// ---------- encoder: out[n,h] = relu(sum_k x[n,k]*WT[k,h] + b[h]) ----------
template <int D>
__global__ __launch_bounds__(256) void encoder_k(const float* __restrict__ x,
                                                 const float* __restrict__ WT,
                                                 const float* __restrict__ b,
                                                 float* __restrict__ out, int N) {
    int idx = blockIdx.x * blockDim.x + threadIdx.x;
    if (idx >= N * HDIM) return;
    int n = idx >> 7, h = idx & 127;
    const float* xr = x + (size_t)n * D;
    float acc = b[h];
#pragma unroll
    for (int k = 0; k < D; k++) acc = fmaf(xr[k], WT[k * HDIM + h], acc);
    out[idx] = fmaxf(acc, 0.f);
}

// ---------- CSR build: counts ----------
__global__ void count_k(const int* __restrict__ ecol, const int* __restrict__ econ,
                        int* cnt_col, int* cnt_con, int E) {
    int e = blockIdx.x * blockDim.x + threadIdx.x;
    if (e < E) {
        atomicAdd(&cnt_col[ecol[e]], 1);
        atomicAdd(&cnt_con[econ[e]], 1);
    }
}

// ---------- 3-phase exclusive scan ----------
__global__ __launch_bounds__(256) void scan1_k(const int* __restrict__ cnt, int n,
                                               int* __restrict__ offs, int* __restrict__ partials) {
    __shared__ int lds[256];
    int t = threadIdx.x;
    int base = blockIdx.x * SCAN_B + t * 4;
    int v[4], s = 0;
#pragma unroll
    for (int i = 0; i < 4; i++) { int idx = base + i; v[i] = (idx < n) ? cnt[idx] : 0; s += v[i]; }
    lds[t] = s; __syncthreads();
    for (int off = 1; off < 256; off <<= 1) {
        int x = (t >= off) ? lds[t - off] : 0; __syncthreads();
        lds[t] += x; __syncthreads();
    }
    int excl = lds[t] - s;
    if (t == 255) partials[blockIdx.x] = lds[255];
    int run = excl;
#pragma unroll
    for (int i = 0; i < 4; i++) { int idx = base + i; if (idx < n) offs[idx] = run; run += v[i]; }
}

__global__ __launch_bounds__(256) void scan2_k(int* partials, int nb) {  // nb <= 256, single block
    __shared__ int lds[256];
    int t = threadIdx.x;
    int v = (t < nb) ? partials[t] : 0;
    lds[t] = v; __syncthreads();
    for (int off = 1; off < 256; off <<= 1) {
        int x = (t >= off) ? lds[t - off] : 0; __syncthreads();
        lds[t] += x; __syncthreads();
    }
    if (t < nb) partials[t] = lds[t] - v;  // exclusive
}

__global__ void scan3_k(int* offs, int n, const int* __restrict__ partials) {
    int i = blockIdx.x * blockDim.x + threadIdx.x;
    if (i < n) offs[i] += partials[i / SCAN_B];
}

// ---------- CSR fill: srclist bucketed by destination ----------
__global__ void fill_k(const int* __restrict__ sidx, const int* __restrict__ didx,
                       const int* __restrict__ offs, int* cursor, int* __restrict__ srclist, int E) {
    int e = blockIdx.x * blockDim.x + threadIdx.x;
    if (e < E) {
        int d = didx[e];
        int p = offs[d] + atomicAdd(&cursor[d], 1);
        srclist[p] = sidx[e];
    }
}

// ---------- gather segment-mean: one wave per dst node, lane owns 2 of 128 cols ----------
__global__ __launch_bounds__(256) void gather_mean_k(const float* __restrict__ tab,
                                                     const int* __restrict__ srclist,
                                                     const int* __restrict__ offs,
                                                     const int* __restrict__ cnt,
                                                     float* __restrict__ out, int N) {
    int wid = threadIdx.x >> 6, lane = threadIdx.x & 63;
    int n = blockIdx.x * 4 + wid;
    if (n >= N) return;
    int c = cnt[n], st = offs[n];
    const int* sl = srclist + st;
    float ax = 0.f, ay = 0.f;
    int j = 0;
    for (; j + 1 < c; j += 2) {
        int s0 = sl[j], s1 = sl[j + 1];
        float2 a = *reinterpret_cast<const float2*>(tab + (size_t)s0 * HDIM + lane * 2);
        float2 b = *reinterpret_cast<const float2*>(tab + (size_t)s1 * HDIM + lane * 2);
        ax += a.x + b.x; ay += a.y + b.y;
    }
    if (j < c) {
        int s0 = sl[j];
        float2 a = *reinterpret_cast<const float2*>(tab + (size_t)s0 * HDIM + lane * 2);
        ax += a.x; ay += a.y;
    }
    float inv = 1.f / fmaxf((float)c, 1.f);
    float2 r; r.x = ax * inv; r.y = ay * inv;
    *reinterpret_cast<float2*>(out + (size_t)n * HDIM + lane * 2) = r;
}

// ---------- SAGE post as LDS-tiled dual GEMM ----------
// out[n,h] = relu( agg[n,:]@WlT[:,h] + x[n,:]@WrT[:,h] + bl[h] ), i.e. [N,256]@[256,128].
// BM=64 rows/block, BN=128 (full), BK=16. 256 thr: tx=t&15 -> cols tx*8..+7, ty=t>>4 -> rows ty*4..+3.
__global__ __launch_bounds__(256) void sage_gemm_k(const float* __restrict__ agg,
                                                   const float* __restrict__ xdst,
                                                   const float* __restrict__ WlT,
                                                   const float* __restrict__ bl,
                                                   const float* __restrict__ WrT,
                                                   float* __restrict__ out, int N) {
    __shared__ float As[64][20];    // pad 16->20: float4-aligned, 2-way bank (free)
    __shared__ float Ws[16][128];
    int t = threadIdx.x;
    int tx = t & 15, ty = t >> 4;
    int n0 = blockIdx.x * 64;
    float acc[4][8];
#pragma unroll
    for (int i = 0; i < 4; i++)
#pragma unroll
        for (int j = 0; j < 8; j++) acc[i][j] = 0.f;

    int ar = t >> 2, akq = (t & 3) * 4;
    int wk = t >> 4, wc = (t & 15) * 8;

    for (int kb = 0; kb < 16; ++kb) {
        const float* src = (kb < 8) ? agg : xdst;
        const float* W = (kb < 8) ? WlT : WrT;
        int k0 = (kb & 7) * 16;
        {
            int row = n0 + ar;
            float4 v = (row < N) ? *reinterpret_cast<const float4*>(src + (size_t)row * HDIM + k0 + akq)
                                 : make_float4(0.f, 0.f, 0.f, 0.f);
            *reinterpret_cast<float4*>(&As[ar][akq]) = v;
        }
        {
            const float* wp = W + (size_t)(k0 + wk) * HDIM + wc;
            *reinterpret_cast<float4*>(&Ws[wk][wc]) = *reinterpret_cast<const float4*>(wp);
            *reinterpret_cast<float4*>(&Ws[wk][wc + 4]) = *reinterpret_cast<const float4*>(wp + 4);
        }
        __syncthreads();
#pragma unroll
        for (int k = 0; k < 16; ++k) {
            float a[4];
#pragma unroll
            for (int i = 0; i < 4; i++) a[i] = As[ty * 4 + i][k];
            float4 w0 = *reinterpret_cast<const float4*>(&Ws[k][tx * 8]);
            float4 w1 = *reinterpret_cast<const float4*>(&Ws[k][tx * 8 + 4]);
            float w[8] = {w0.x, w0.y, w0.z, w0.w, w1.x, w1.y, w1.z, w1.w};
#pragma unroll
            for (int i = 0; i < 4; i++)
#pragma unroll
                for (int j = 0; j < 8; j++) acc[i][j] = fmaf(a[i], w[j], acc[i][j]);
        }
        __syncthreads();
    }
    float4 b0 = *reinterpret_cast<const float4*>(bl + tx * 8);
    float4 b1 = *reinterpret_cast<const float4*>(bl + tx * 8 + 4);
    float bb[8] = {b0.x, b0.y, b0.z, b0.w, b1.x, b1.y, b1.z, b1.w};
#pragma unroll
    for (int i = 0; i < 4; i++) {
        int row = n0 + ty * 4 + i;
        if (row < N) {
            float4 r0, r1;
            r0.x = fmaxf(acc[i][0] + bb[0], 0.f);
            r0.y = fmaxf(acc[i][1] + bb[1], 0.f);
            r0.z = fmaxf(acc[i][2] + bb[2], 0.f);
            r0.w = fmaxf(acc[i][3] + bb[3], 0.f);
            r1.x = fmaxf(acc[i][4] + bb[4], 0.f);
            r1.y = fmaxf(acc[i][5] + bb[5], 0.f);
            r1.z = fmaxf(acc[i][6] + bb[6], 0.f);
            r1.w = fmaxf(acc[i][7] + bb[7], 0.f);
            float* op = out + (size_t)row * HDIM + tx * 8;
            *reinterpret_cast<float4*>(op) = r0;
            *reinterpret_cast<float4*>(op + 4) = r1;
        }
    }
}

// ---------- conv2 GEMM fused with Q-head ----------
// Phase 1: h2 tile = relu(agg@WlT + x@WrT + bl) -> LDS (never touches global).
// Phase 2: y = relu(h2 @ W1T + b1) [64x64]; q = y @ W2 + b2 -> out[n].
__global__ __launch_bounds__(256) void sage_gemm_q_k(const float* __restrict__ agg,
                                                     const float* __restrict__ xdst,
                                                     const float* __restrict__ WlT,
                                                     const float* __restrict__ bl,
                                                     const float* __restrict__ WrT,
                                                     const float* __restrict__ W1T,
                                                     const float* __restrict__ b1v,
                                                     const float* __restrict__ W2,
                                                     const float* __restrict__ b2,
                                                     float* __restrict__ out, int N) {
    __shared__ float As[64][20];
    __shared__ float Ws[16][128];
    __shared__ float H2[64][132];   // pad 128->132: 2-way bank on phase-2 reads (free)
    int t = threadIdx.x;
    int tx = t & 15, ty = t >> 4;
    int n0 = blockIdx.x * 64;
    float acc[4][8];
#pragma unroll
    for (int i = 0; i < 4; i++)
#pragma unroll
        for (int j = 0; j < 8; j++) acc[i][j] = 0.f;

    int ar = t >> 2, akq = (t & 3) * 4;
    int wk = t >> 4, wc = (t & 15) * 8;

    for (int kb = 0; kb < 16; ++kb) {
        const float* src = (kb < 8) ? agg : xdst;
        const float* W = (kb < 8) ? WlT : WrT;
        int k0 = (kb & 7) * 16;
        {
            int row = n0 + ar;
            float4 v = (row < N) ? *reinterpret_cast<const float4*>(src + (size_t)row * HDIM + k0 + akq)
                                 : make_float4(0.f, 0.f, 0.f, 0.f);
            *reinterpret_cast<float4*>(&As[ar][akq]) = v;
        }
        {
            const float* wp = W + (size_t)(k0 + wk) * HDIM + wc;
            *reinterpret_cast<float4*>(&Ws[wk][wc]) = *reinterpret_cast<const float4*>(wp);
            *reinterpret_cast<float4*>(&Ws[wk][wc + 4]) = *reinterpret_cast<const float4*>(wp + 4);
        }
        __syncthreads();
#pragma unroll
        for (int k = 0; k < 16; ++k) {
            float a[4];
#pragma unroll
            for (int i = 0; i < 4; i++) a[i] = As[ty * 4 + i][k];
            float4 w0 = *reinterpret_cast<const float4*>(&Ws[k][tx * 8]);
            float4 w1 = *reinterpret_cast<const float4*>(&Ws[k][tx * 8 + 4]);
            float w[8] = {w0.x, w0.y, w0.z, w0.w, w1.x, w1.y, w1.z, w1.w};
#pragma unroll
            for (int i = 0; i < 4; i++)
#pragma unroll
                for (int j = 0; j < 8; j++) acc[i][j] = fmaf(a[i], w[j], acc[i][j]);
        }
        __syncthreads();
    }
    // phase-1 epilogue: bias + relu -> LDS tile
    {
        float4 b0 = *reinterpret_cast<const float4*>(bl + tx * 8);
        float4 b1 = *reinterpret_cast<const float4*>(bl + tx * 8 + 4);
        float bb[8] = {b0.x, b0.y, b0.z, b0.w, b1.x, b1.y, b1.z, b1.w};
#pragma unroll
        for (int i = 0; i < 4; i++) {
            float4 r0, r1;
            r0.x = fmaxf(acc[i][0] + bb[0], 0.f);
            r0.y = fmaxf(acc[i][1] + bb[1], 0.f);
            r0.z = fmaxf(acc[i][2] + bb[2], 0.f);
            r0.w = fmaxf(acc[i][3] + bb[3], 0.f);
            r1.x = fmaxf(acc[i][4] + bb[4], 0.f);
            r1.y = fmaxf(acc[i][5] + bb[5], 0.f);
            r1.z = fmaxf(acc[i][6] + bb[6], 0.f);
            r1.w = fmaxf(acc[i][7] + bb[7], 0.f);
            float* hp = &H2[ty * 4 + i][tx * 8];
            *reinterpret_cast<float4*>(hp) = r0;
            *reinterpret_cast<float4*>(hp + 4) = r1;
        }
    }
    __syncthreads();
    // phase 2: rows ty2*2..+1, cols tx2*8..+7 of y[64][64]
    int tx2 = t & 7, ty2 = t >> 3;
    float acc2[2][8];
#pragma unroll
    for (int i = 0; i < 2; i++)
#pragma unroll
        for (int j = 0; j < 8; j++) acc2[i][j] = 0.f;
    for (int k4 = 0; k4 < HDIM / 4; ++k4) {
        float4 a0 = *reinterpret_cast<const float4*>(&H2[ty2 * 2 + 0][k4 * 4]);
        float4 a1 = *reinterpret_cast<const float4*>(&H2[ty2 * 2 + 1][k4 * 4]);
        float a[2][4] = {{a0.x, a0.y, a0.z, a0.w}, {a1.x, a1.y, a1.z, a1.w}};
#pragma unroll
        for (int kk = 0; kk < 4; kk++) {
            const float* wp = W1T + (size_t)(k4 * 4 + kk) * 64 + tx2 * 8;
            float4 w0 = *reinterpret_cast<const float4*>(wp);
            float4 w1 = *reinterpret_cast<const float4*>(wp + 4);
            float w[8] = {w0.x, w0.y, w0.z, w0.w, w1.x, w1.y, w1.z, w1.w};
#pragma unroll
            for (int i = 0; i < 2; i++)
#pragma unroll
                for (int j = 0; j < 8; j++) acc2[i][j] = fmaf(a[i][kk], w[j], acc2[i][j]);
        }
    }
    // phase-2 epilogue: relu(+b1) dot W2, 8-lane reduce, +b2
    {
        float4 c0 = *reinterpret_cast<const float4*>(b1v + tx2 * 8);
        float4 c1 = *reinterpret_cast<const float4*>(b1v + tx2 * 8 + 4);
        float bb1[8] = {c0.x, c0.y, c0.z, c0.w, c1.x, c1.y, c1.z, c1.w};
        float4 d0 = *reinterpret_cast<const float4*>(W2 + tx2 * 8);
        float4 d1 = *reinterpret_cast<const float4*>(W2 + tx2 * 8 + 4);
        float w2[8] = {d0.x, d0.y, d0.z, d0.w, d1.x, d1.y, d1.z, d1.w};
#pragma unroll
        for (int i = 0; i < 2; i++) {
            float v = 0.f;
#pragma unroll
            for (int j = 0; j < 8; j++) v = fmaf(fmaxf(acc2[i][j] + bb1[j], 0.f), w2[j], v);
            v += __shfl_xor(v, 1);
            v += __shfl_xor(v, 2);
            v += __shfl_xor(v, 4);
            int row = n0 + ty2 * 2 + i;
            if (tx2 == 0 && row < N) out[row] = v + b2[0];
        }
    }
}

extern "C" void kernel_launch(void* const* d_in, const int* in_sizes, int n_in,
                              void* d_out, int out_size, void* d_ws, size_t ws_size,
                              hipStream_t stream) {
    const float* x_col = (const float*)d_in[0];
    const float* x_con = (const float*)d_in[1];
    const int* edge_col = (const int*)d_in[2];
    const int* edge_con = (const int*)d_in[3];
    const float* W_col = (const float*)d_in[4];
    const float* b_col = (const float*)d_in[5];
    const float* W_con = (const float*)d_in[6];
    const float* b_con = (const float*)d_in[7];
    const float* c1_cn_Wl = (const float*)d_in[8];
    const float* c1_cn_bl = (const float*)d_in[9];
    const float* c1_cn_Wr = (const float*)d_in[10];
    const float* c1_nc_Wl = (const float*)d_in[11];
    const float* c1_nc_bl = (const float*)d_in[12];
    const float* c1_nc_Wr = (const float*)d_in[13];
    // d_in[14..16] = c2_cn_* : dead (h_con2 deleted in reference)
    const float* c2_nc_Wl = (const float*)d_in[17];
    const float* c2_nc_bl = (const float*)d_in[18];
    const float* c2_nc_Wr = (const float*)d_in[19];
    const float* q_W1 = (const float*)d_in[20];
    const float* q_b1 = (const float*)d_in[21];
    const float* q_W2 = (const float*)d_in[22];
    const float* q_b2 = (const float*)d_in[23];
    float* out = (float*)d_out;
    const int E = in_sizes[2];

    float* ws = (float*)d_ws;
    size_t o = 0;
    float* h_col = ws + o;   o += (size_t)N_COL * HDIM;
    float* h_con = ws + o;   o += (size_t)N_CON * HDIM;
    float* agg_con = ws + o; o += (size_t)N_CON * HDIM;
    float* n_con = ws + o;   o += (size_t)N_CON * HDIM;
    float* agg_col = ws + o; o += (size_t)N_COL * HDIM;
    float* n_col = ws + o;   o += (size_t)N_COL * HDIM;
    float* W_colT = ws + o;  o += 16 * HDIM;
    float* W_conT = ws + o;  o += 8 * HDIM;
    float* c1_cn_WlT = ws + o; o += HDIM * HDIM;
    float* c1_cn_WrT = ws + o; o += HDIM * HDIM;
    float* c1_nc_WlT = ws + o; o += HDIM * HDIM;
    float* c1_nc_WrT = ws + o; o += HDIM * HDIM;
    float* c2_nc_WlT = ws + o; o += HDIM * HDIM;
    float* c2_nc_WrT = ws + o; o += HDIM * HDIM;
    float* q_W1T = ws + o;     o += HDIM * 64;
    // CSR scratch (int views)
    int* iws = (int*)(ws + o);
    size_t io = 0;
    int* cnt_col = iws + io;  io += N_COL;
    int* cnt_con = iws + io;  io += N_CON;
    int* offs_col = iws + io; io += N_COL;
    int* offs_con = iws + io; io += N_CON;
    int* cursor = iws + io;   io += N_COL;  // reused for both fills
    int* partials = iws + io; io += 256;
    int* srclist_col = iws + io; io += E;   // dst=col buckets, stores con src idx
    int* srclist_con = iws + io; io += E;   // dst=con buckets, stores col src idx

    auto T = [&](const float* s, float* d, int R, int C) {
        transpose_k<<<(R * C + 255) / 256, 256, 0, stream>>>(s, d, R, C);
    };
    T(W_col, W_colT, HDIM, 16);
    T(W_con, W_conT, HDIM, 8);
    T(c1_cn_Wl, c1_cn_WlT, HDIM, HDIM);
    T(c1_cn_Wr, c1_cn_WrT, HDIM, HDIM);
    T(c1_nc_Wl, c1_nc_WlT, HDIM, HDIM);
    T(c1_nc_Wr, c1_nc_WrT, HDIM, HDIM);
    T(c2_nc_Wl, c2_nc_WlT, HDIM, HDIM);
    T(c2_nc_Wr, c2_nc_WrT, HDIM, HDIM);
    T(q_W1, q_W1T, 64, HDIM);

    encoder_k<16><<<((size_t)N_COL * HDIM + 255) / 256, 256, 0, stream>>>(x_col, W_colT, b_col, h_col, N_COL);
    encoder_k<8><<<((size_t)N_CON * HDIM + 255) / 256, 256, 0, stream>>>(x_con, W_conT, b_con, h_con, N_CON);

    // ---- CSR build (both directions) ----
    hipMemsetAsync(cnt_col, 0, (N_COL + N_CON) * sizeof(int), stream);  // cnt_col+cnt_con contiguous
    count_k<<<(E + 255) / 256, 256, 0, stream>>>(edge_col, edge_con, cnt_col, cnt_con, E);

    int nb_col = (N_COL + SCAN_B - 1) / SCAN_B;  // 98
    int nb_con = (N_CON + SCAN_B - 1) / SCAN_B;  // 20
    scan1_k<<<nb_col, 256, 0, stream>>>(cnt_col, N_COL, offs_col, partials);
    scan2_k<<<1, 256, 0, stream>>>(partials, nb_col);
    scan3_k<<<(N_COL + 255) / 256, 256, 0, stream>>>(offs_col, N_COL, partials);
    scan1_k<<<nb_con, 256, 0, stream>>>(cnt_con, N_CON, offs_con, partials);
    scan2_k<<<1, 256, 0, stream>>>(partials, nb_con);
    scan3_k<<<(N_CON + 255) / 256, 256, 0, stream>>>(offs_con, N_CON, partials);

    hipMemsetAsync(cursor, 0, N_COL * sizeof(int), stream);
    fill_k<<<(E + 255) / 256, 256, 0, stream>>>(edge_con, edge_col, offs_col, cursor, srclist_col, E);
    hipMemsetAsync(cursor, 0, N_CON * sizeof(int), stream);
    fill_k<<<(E + 255) / 256, 256, 0, stream>>>(edge_col, edge_con, offs_con, cursor, srclist_con, E);

    // ---- conv1 col->con ----
    gather_mean_k<<<(N_CON + 3) / 4, 256, 0, stream>>>(h_col, srclist_con, offs_con, cnt_con, agg_con, N_CON);
    sage_gemm_k<<<(N_CON + 63) / 64, 256, 0, stream>>>(agg_con, h_con, c1_cn_WlT, c1_cn_bl, c1_cn_WrT, n_con, N_CON);

    // ---- conv1 con->col ----
    gather_mean_k<<<(N_COL + 3) / 4, 256, 0, stream>>>(h_con, srclist_col, offs_col, cnt_col, agg_col, N_COL);
    sage_gemm_k<<<(N_COL + 63) / 64, 256, 0, stream>>>(agg_col, h_col, c1_nc_WlT, c1_nc_bl, c1_nc_WrT, n_col, N_COL);

    // ---- conv2 con->col (col->con branch dead) + fused Q-head ----
    gather_mean_k<<<(N_COL + 3) / 4, 256, 0, stream>>>(n_con, srclist_col, offs_col, cnt_col, agg_col, N_COL);
    sage_gemm_q_k<<<(N_COL + 63) / 64, 256, 0, stream>>>(agg_col, n_col, c2_nc_WlT, c2_nc_bl, c2_nc_WrT,
                                                         q_W1T, q_b1, q_W2, q_b2, out, N_COL);
}

// Round 6
// 787.480 us; speedup vs baseline: 6.9019x; 1.0563x over previous
//
#include <hip/hip_runtime.h>

#define N_COL 100000
#define N_CON 20000
#define HDIM 128
#define SCAN_B 1024  // elements scanned per block (256 thr x 4)

// ---------- tiny transpose: dst[c*R+r] = src[r*C+c] ----------
__global__ void transpose_k(const float* __restrict__ src, float* __restrict__ dst, int R, int C) {
    int idx = blockIdx.x * blockDim.x + threadIdx.x;
    if (idx < R * C) {
        int r = idx / C, c = idx - r * C;
        dst[c * R + r] = src[idx];
    }
}

// ---------- encoder: out[n,h] = relu(sum_k x[n,k]*WT[k,h] + b[h]) ----------
template <int D>
__global__ __launch_bounds__(256) void encoder_k(const float* __restrict__ x,
                                                 const float* __restrict__ WT,
                                                 const float* __restrict__ b,
                                                 float* __restrict__ out, int N) {
    int idx = blockIdx.x * blockDim.x + threadIdx.x;
    if (idx >= N * HDIM) return;
    int n = idx >> 7, h = idx & 127;
    const float* xr = x + (size_t)n * D;
    float acc = b[h];
#pragma unroll
    for (int k = 0; k < D; k++) acc = fmaf(xr[k], WT[k * HDIM + h], acc);
    out[idx] = fmaxf(acc, 0.f);
}

// ---------- CSR build: counts ----------
__global__ void count_k(const int* __restrict__ ecol, const int* __restrict__ econ,
                        int* cnt_col, int* cnt_con, int E) {
    int e = blockIdx.x * blockDim.x + threadIdx.x;
    if (e < E) {
        atomicAdd(&cnt_col[ecol[e]], 1);
        atomicAdd(&cnt_con[econ[e]], 1);
    }
}

// ---------- 3-phase exclusive scan ----------
__global__ __launch_bounds__(256) void scan1_k(const int* __restrict__ cnt, int n,
                                               int* __restrict__ offs, int* __restrict__ partials) {
    __shared__ int lds[256];
    int t = threadIdx.x;
    int base = blockIdx.x * SCAN_B + t * 4;
    int v[4], s = 0;
#pragma unroll
    for (int i = 0; i < 4; i++) { int idx = base + i; v[i] = (idx < n) ? cnt[idx] : 0; s += v[i]; }
    lds[t] = s; __syncthreads();
    for (int off = 1; off < 256; off <<= 1) {
        int x = (t >= off) ? lds[t - off] : 0; __syncthreads();
        lds[t] += x; __syncthreads();
    }
    int excl = lds[t] - s;
    if (t == 255) partials[blockIdx.x] = lds[255];
    int run = excl;
#pragma unroll
    for (int i = 0; i < 4; i++) { int idx = base + i; if (idx < n) offs[idx] = run; run += v[i]; }
}

__global__ __launch_bounds__(256) void scan2_k(int* partials, int nb) {  // nb <= 256, single block
    __shared__ int lds[256];
    int t = threadIdx.x;
    int v = (t < nb) ? partials[t] : 0;
    lds[t] = v; __syncthreads();
    for (int off = 1; off < 256; off <<= 1) {
        int x = (t >= off) ? lds[t - off] : 0; __syncthreads();
        lds[t] += x; __syncthreads();
    }
    if (t < nb) partials[t] = lds[t] - v;  // exclusive
}

__global__ void scan3_k(int* offs, int n, const int* __restrict__ partials) {
    int i = blockIdx.x * blockDim.x + threadIdx.x;
    if (i < n) offs[i] += partials[i / SCAN_B];
}

// ---------- CSR fill: srclist bucketed by destination ----------
__global__ void fill_k(const int* __restrict__ sidx, const int* __restrict__ didx,
                       const int* __restrict__ offs, int* cursor, int* __restrict__ srclist, int E) {
    int e = blockIdx.x * blockDim.x + threadIdx.x;
    if (e < E) {
        int d = didx[e];
        int p = offs[d] + atomicAdd(&cursor[d], 1);
        srclist[p] = sidx[e];
    }
}

// ---------- gather segment-mean: one wave per dst node ----------
// lane halves process 2 edges in parallel; lane owns float4 of cols (lane&31)*4.
__global__ __launch_bounds__(256) void gather_mean_k(const float* __restrict__ tab,
                                                     const int* __restrict__ srclist,
                                                     const int* __restrict__ offs,
                                                     const int* __restrict__ cnt,
                                                     float* __restrict__ out, int N) {
    int wid = threadIdx.x >> 6, lane = threadIdx.x & 63;
    int n = blockIdx.x * 4 + wid;
    if (n >= N) return;
    int c = cnt[n], st = offs[n];
    const int* sl = srclist + st;
    int half = lane >> 5, q = (lane & 31) * 4;
    float ax = 0.f, ay = 0.f, az = 0.f, aw = 0.f;
    int j = 0;
    for (; j + 1 < c; j += 2) {
        int s = sl[j + half];
        float4 a = *reinterpret_cast<const float4*>(tab + (size_t)s * HDIM + q);
        ax += a.x; ay += a.y; az += a.z; aw += a.w;
    }
    if (j < c && half == 0) {
        int s = sl[j];
        float4 a = *reinterpret_cast<const float4*>(tab + (size_t)s * HDIM + q);
        ax += a.x; ay += a.y; az += a.z; aw += a.w;
    }
    ax += __shfl_xor(ax, 32); ay += __shfl_xor(ay, 32);
    az += __shfl_xor(az, 32); aw += __shfl_xor(aw, 32);
    if (half == 0) {
        float inv = 1.f / fmaxf((float)c, 1.f);
        float4 r; r.x = ax * inv; r.y = ay * inv; r.z = az * inv; r.w = aw * inv;
        *reinterpret_cast<float4*>(out + (size_t)n * HDIM + q) = r;
    }
}

// ======== shared GEMM phase-1 body (BM=64, BN=128, BK=32) ========
// thread cols: {tx*4..+3} and {64+tx*4..+3}  (stride-4 LDS reads -> 2-way bank, free)
#define GEMM_PHASE1(As, Ws, acc)                                                            \
    int tx = t & 15, ty = t >> 4;                                                           \
    int ar = t >> 2, akq = (t & 3) * 8;                                                     \
    int wk = t >> 3, wc = (t & 7) * 16;                                                     \
    for (int half = 0; half < 2; ++half) {                                                  \
        const float* src = half ? xdst : agg;                                               \
        const float* W = half ? WrT : WlT;                                                  \
        for (int kb = 0; kb < 4; ++kb) {                                                    \
            int k0 = kb * 32;                                                               \
            {                                                                               \
                int row = n0 + ar;                                                          \
                float4 v0 = make_float4(0.f, 0.f, 0.f, 0.f), v1 = v0;                       \
                if (row < N) {                                                              \
                    const float* ap = src + (size_t)row * HDIM + k0 + akq;                  \
                    v0 = *reinterpret_cast<const float4*>(ap);                              \
                    v1 = *reinterpret_cast<const float4*>(ap + 4);                          \
                }                                                                           \
                *reinterpret_cast<float4*>(&As[ar][akq]) = v0;                              \
                *reinterpret_cast<float4*>(&As[ar][akq + 4]) = v1;                          \
            }                                                                               \
            {                                                                               \
                const float* wp = W + (size_t)(k0 + wk) * HDIM + wc;                        \
                _Pragma("unroll")                                                           \
                for (int jj = 0; jj < 4; jj++)                                              \
                    *reinterpret_cast<float4*>(&Ws[wk][wc + 4 * jj]) =                      \
                        *reinterpret_cast<const float4*>(wp + 4 * jj);                      \
            }                                                                               \
            __syncthreads();                                                                \
            _Pragma("unroll")                                                               \
            for (int k = 0; k < 32; ++k) {                                                  \
                float a[4];                                                                 \
                _Pragma("unroll")                                                           \
                for (int i = 0; i < 4; i++) a[i] = As[ty * 4 + i][k];                       \
                float4 w0 = *reinterpret_cast<const float4*>(&Ws[k][tx * 4]);               \
                float4 w1 = *reinterpret_cast<const float4*>(&Ws[k][64 + tx * 4]);          \
                float w[8] = {w0.x, w0.y, w0.z, w0.w, w1.x, w1.y, w1.z, w1.w};              \
                _Pragma("unroll")                                                           \
                for (int i = 0; i < 4; i++)                                                 \
                    _Pragma("unroll")                                                       \
                    for (int j = 0; j < 8; j++) acc[i][j] = fmaf(a[i], w[j], acc[i][j]);    \
            }                                                                               \
            __syncthreads();                                                                \
        }                                                                                   \
    }

// ---------- SAGE post as LDS-tiled dual GEMM ----------
__global__ __launch_bounds__(256) void sage_gemm_k(const float* __restrict__ agg,
                                                   const float* __restrict__ xdst,
                                                   const float* __restrict__ WlT,
                                                   const float* __restrict__ bl,
                                                   const float* __restrict__ WrT,
                                                   float* __restrict__ out, int N) {
    __shared__ __align__(16) char smem[26112];  // As 9216 + Ws 16896
    float (*As)[36] = reinterpret_cast<float(*)[36]>(smem);
    float (*Ws)[132] = reinterpret_cast<float(*)[132]>(smem + 9216);
    int t = threadIdx.x;
    int n0 = blockIdx.x * 64;
    float acc[4][8];
#pragma unroll
    for (int i = 0; i < 4; i++)
#pragma unroll
        for (int j = 0; j < 8; j++) acc[i][j] = 0.f;

    GEMM_PHASE1(As, Ws, acc)

    float4 b0 = *reinterpret_cast<const float4*>(bl + tx * 4);
    float4 b1 = *reinterpret_cast<const float4*>(bl + 64 + tx * 4);
    float bb[8] = {b0.x, b0.y, b0.z, b0.w, b1.x, b1.y, b1.z, b1.w};
#pragma unroll
    for (int i = 0; i < 4; i++) {
        int row = n0 + ty * 4 + i;
        if (row < N) {
            float4 r0, r1;
            r0.x = fmaxf(acc[i][0] + bb[0], 0.f);
            r0.y = fmaxf(acc[i][1] + bb[1], 0.f);
            r0.z = fmaxf(acc[i][2] + bb[2], 0.f);
            r0.w = fmaxf(acc[i][3] + bb[3], 0.f);
            r1.x = fmaxf(acc[i][4] + bb[4], 0.f);
            r1.y = fmaxf(acc[i][5] + bb[5], 0.f);
            r1.z = fmaxf(acc[i][6] + bb[6], 0.f);
            r1.w = fmaxf(acc[i][7] + bb[7], 0.f);
            float* op = out + (size_t)row * HDIM;
            *reinterpret_cast<float4*>(op + tx * 4) = r0;
            *reinterpret_cast<float4*>(op + 64 + tx * 4) = r1;
        }
    }
}

// ---------- conv2 GEMM fused with Q-head (H2 tile stays in LDS, unioned with As/Ws) ----------
__global__ __launch_bounds__(256) void sage_gemm_q_k(const float* __restrict__ agg,
                                                     const float* __restrict__ xdst,
                                                     const float* __restrict__ WlT,
                                                     const float* __restrict__ bl,
                                                     const float* __restrict__ WrT,
                                                     const float* __restrict__ W1T,
                                                     const float* __restrict__ b1v,
                                                     const float* __restrict__ W2,
                                                     const float* __restrict__ b2,
                                                     float* __restrict__ out, int N) {
    __shared__ __align__(16) char smem[33792];  // union: (As 9216 + Ws 16896) | H2 33792
    float (*As)[36] = reinterpret_cast<float(*)[36]>(smem);
    float (*Ws)[132] = reinterpret_cast<float(*)[132]>(smem + 9216);
    float (*H2)[132] = reinterpret_cast<float(*)[132]>(smem);
    int t = threadIdx.x;
    int n0 = blockIdx.x * 64;
    float acc[4][8];
#pragma unroll
    for (int i = 0; i < 4; i++)
#pragma unroll
        for (int j = 0; j < 8; j++) acc[i][j] = 0.f;

    GEMM_PHASE1(As, Ws, acc)
    // (last __syncthreads of phase 1 protects the As/Ws -> H2 overlay)

    // phase-1 epilogue: bias + relu -> LDS tile
    {
        float4 b0 = *reinterpret_cast<const float4*>(bl + tx * 4);
        float4 b1 = *reinterpret_cast<const float4*>(bl + 64 + tx * 4);
        float bb[8] = {b0.x, b0.y, b0.z, b0.w, b1.x, b1.y, b1.z, b1.w};
#pragma unroll
        for (int i = 0; i < 4; i++) {
            float4 r0, r1;
            r0.x = fmaxf(acc[i][0] + bb[0], 0.f);
            r0.y = fmaxf(acc[i][1] + bb[1], 0.f);
            r0.z = fmaxf(acc[i][2] + bb[2], 0.f);
            r0.w = fmaxf(acc[i][3] + bb[3], 0.f);
            r1.x = fmaxf(acc[i][4] + bb[4], 0.f);
            r1.y = fmaxf(acc[i][5] + bb[5], 0.f);
            r1.z = fmaxf(acc[i][6] + bb[6], 0.f);
            r1.w = fmaxf(acc[i][7] + bb[7], 0.f);
            float* hp = &H2[ty * 4 + i][0];
            *reinterpret_cast<float4*>(hp + tx * 4) = r0;
            *reinterpret_cast<float4*>(hp + 64 + tx * 4) = r1;
        }
    }
    __syncthreads();
    // phase 2: y = relu(H2 @ W1T + b1) [64x64]; q = y@W2 + b2
    int tx2 = t & 7, ty2 = t >> 3;
    float acc2[2][8];
#pragma unroll
    for (int i = 0; i < 2; i++)
#pragma unroll
        for (int j = 0; j < 8; j++) acc2[i][j] = 0.f;
    for (int k4 = 0; k4 < HDIM / 4; ++k4) {
        float4 a0 = *reinterpret_cast<const float4*>(&H2[ty2 * 2 + 0][k4 * 4]);
        float4 a1 = *reinterpret_cast<const float4*>(&H2[ty2 * 2 + 1][k4 * 4]);
        float a[2][4] = {{a0.x, a0.y, a0.z, a0.w}, {a1.x, a1.y, a1.z, a1.w}};
#pragma unroll
        for (int kk = 0; kk < 4; kk++) {
            const float* wp = W1T + (size_t)(k4 * 4 + kk) * 64 + tx2 * 8;
            float4 w0 = *reinterpret_cast<const float4*>(wp);
            float4 w1 = *reinterpret_cast<const float4*>(wp + 4);
            float w[8] = {w0.x, w0.y, w0.z, w0.w, w1.x, w1.y, w1.z, w1.w};
#pragma unroll
            for (int i = 0; i < 2; i++)
#pragma unroll
                for (int j = 0; j < 8; j++) acc2[i][j] = fmaf(a[i][kk], w[j], acc2[i][j]);
        }
    }
    {
        float4 c0 = *reinterpret_cast<const float4*>(b1v + tx2 * 8);
        float4 c1 = *reinterpret_cast<const float4*>(b1v + tx2 * 8 + 4);
        float bb1[8] = {c0.x, c0.y, c0.z, c0.w, c1.x, c1.y, c1.z, c1.w};
        float4 d0 = *reinterpret_cast<const float4*>(W2 + tx2 * 8);
        float4 d1 = *reinterpret_cast<const float4*>(W2 + tx2 * 8 + 4);
        float w2[8] = {d0.x, d0.y, d0.z, d0.w, d1.x, d1.y, d1.z, d1.w};
#pragma unroll
        for (int i = 0; i < 2; i++) {
            float v = 0.f;
#pragma unroll
            for (int j = 0; j < 8; j++) v = fmaf(fmaxf(acc2[i][j] + bb1[j], 0.f), w2[j], v);
            v += __shfl_xor(v, 1);
            v += __shfl_xor(v, 2);
            v += __shfl_xor(v, 4);
            int row = n0 + ty2 * 2 + i;
            if (tx2 == 0 && row < N) out[row] = v + b2[0];
        }
    }
}

extern "C" void kernel_launch(void* const* d_in, const int* in_sizes, int n_in,
                              void* d_out, int out_size, void* d_ws, size_t ws_size,
                              hipStream_t stream) {
    const float* x_col = (const float*)d_in[0];
    const float* x_con = (const float*)d_in[1];
    const int* edge_col = (const int*)d_in[2];
    const int* edge_con = (const int*)d_in[3];
    const float* W_col = (const float*)d_in[4];
    const float* b_col = (const float*)d_in[5];
    const float* W_con = (const float*)d_in[6];
    const float* b_con = (const float*)d_in[7];
    const float* c1_cn_Wl = (const float*)d_in[8];
    const float* c1_cn_bl = (const float*)d_in[9];
    const float* c1_cn_Wr = (const float*)d_in[10];
    const float* c1_nc_Wl = (const float*)d_in[11];
    const float* c1_nc_bl = (const float*)d_in[12];
    const float* c1_nc_Wr = (const float*)d_in[13];
    // d_in[14..16] = c2_cn_* : dead (h_con2 deleted in reference)
    const float* c2_nc_Wl = (const float*)d_in[17];
    const float* c2_nc_bl = (const float*)d_in[18];
    const float* c2_nc_Wr = (const float*)d_in[19];
    const float* q_W1 = (const float*)d_in[20];
    const float* q_b1 = (const float*)d_in[21];
    const float* q_W2 = (const float*)d_in[22];
    const float* q_b2 = (const float*)d_in[23];
    float* out = (float*)d_out;
    const int E = in_sizes[2];

    float* ws = (float*)d_ws;
    size_t o = 0;
    float* h_col = ws + o;   o += (size_t)N_COL * HDIM;
    float* h_con = ws + o;   o += (size_t)N_CON * HDIM;
    float* agg_con = ws + o; o += (size_t)N_CON * HDIM;
    float* n_con = ws + o;   o += (size_t)N_CON * HDIM;
    float* agg_col = ws + o; o += (size_t)N_COL * HDIM;
    float* n_col = ws + o;   o += (size_t)N_COL * HDIM;
    float* W_colT = ws + o;  o += 16 * HDIM;
    float* W_conT = ws + o;  o += 8 * HDIM;
    float* c1_cn_WlT = ws + o; o += HDIM * HDIM;
    float* c1_cn_WrT = ws + o; o += HDIM * HDIM;
    float* c1_nc_WlT = ws + o; o += HDIM * HDIM;
    float* c1_nc_WrT = ws + o; o += HDIM * HDIM;
    float* c2_nc_WlT = ws + o; o += HDIM * HDIM;
    float* c2_nc_WrT = ws + o; o += HDIM * HDIM;
    float* q_W1T = ws + o;     o += HDIM * 64;
    // CSR scratch (int views)
    int* iws = (int*)(ws + o);
    size_t io = 0;
    int* cnt_col = iws + io;  io += N_COL;
    int* cnt_con = iws + io;  io += N_CON;
    int* offs_col = iws + io; io += N_COL;
    int* offs_con = iws + io; io += N_CON;
    int* cursor = iws + io;   io += N_COL;  // reused for both fills
    int* partials = iws + io; io += 256;
    int* srclist_col = iws + io; io += E;   // dst=col buckets, stores con src idx
    int* srclist_con = iws + io; io += E;   // dst=con buckets, stores col src idx

    auto T = [&](const float* s, float* d, int R, int C) {
        transpose_k<<<(R * C + 255) / 256, 256, 0, stream>>>(s, d, R, C);
    };
    T(W_col, W_colT, HDIM, 16);
    T(W_con, W_conT, HDIM, 8);
    T(c1_cn_Wl, c1_cn_WlT, HDIM, HDIM);
    T(c1_cn_Wr, c1_cn_WrT, HDIM, HDIM);
    T(c1_nc_Wl, c1_nc_WlT, HDIM, HDIM);
    T(c1_nc_Wr, c1_nc_WrT, HDIM, HDIM);
    T(c2_nc_Wl, c2_nc_WlT, HDIM, HDIM);
    T(c2_nc_Wr, c2_nc_WrT, HDIM, HDIM);
    T(q_W1, q_W1T, 64, HDIM);

    encoder_k<16><<<((size_t)N_COL * HDIM + 255) / 256, 256, 0, stream>>>(x_col, W_colT, b_col, h_col, N_COL);
    encoder_k<8><<<((size_t)N_CON * HDIM + 255) / 256, 256, 0, stream>>>(x_con, W_conT, b_con, h_con, N_CON);

    // ---- CSR build (both directions) ----
    hipMemsetAsync(cnt_col, 0, (N_COL + N_CON) * sizeof(int), stream);  // cnt_col+cnt_con contiguous
    count_k<<<(E + 255) / 256, 256, 0, stream>>>(edge_col, edge_con, cnt_col, cnt_con, E);

    int nb_col = (N_COL + SCAN_B - 1) / SCAN_B;  // 98
    int nb_con = (N_CON + SCAN_B - 1) / SCAN_B;  // 20
    scan1_k<<<nb_col, 256, 0, stream>>>(cnt_col, N_COL, offs_col, partials);
    scan2_k<<<1, 256, 0, stream>>>(partials, nb_col);
    scan3_k<<<(N_COL + 255) / 256, 256, 0, stream>>>(offs_col, N_COL, partials);
    scan1_k<<<nb_con, 256, 0, stream>>>(cnt_con, N_CON, offs_con, partials);
    scan2_k<<<1, 256, 0, stream>>>(partials, nb_con);
    scan3_k<<<(N_CON + 255) / 256, 256, 0, stream>>>(offs_con, N_CON, partials);

    hipMemsetAsync(cursor, 0, N_COL * sizeof(int), stream);
    fill_k<<<(E + 255) / 256, 256, 0, stream>>>(edge_con, edge_col, offs_col, cursor, srclist_col, E);
    hipMemsetAsync(cursor, 0, N_CON * sizeof(int), stream);
    fill_k<<<(E + 255) / 256, 256, 0, stream>>>(edge_col, edge_con, offs_con, cursor, srclist_con, E);

    // ---- conv1 col->con ----
    gather_mean_k<<<(N_CON + 3) / 4, 256, 0, stream>>>(h_col, srclist_con, offs_con, cnt_con, agg_con, N_CON);
    sage_gemm_k<<<(N_CON + 63) / 64, 256, 0, stream>>>(agg_con, h_con, c1_cn_WlT, c1_cn_bl, c1_cn_WrT, n_con, N_CON);

    // ---- conv1 con->col ----
    gather_mean_k<<<(N_COL + 3) / 4, 256, 0, stream>>>(h_con, srclist_col, offs_col, cnt_col, agg_col, N_COL);
    sage_gemm_k<<<(N_COL + 63) / 64, 256, 0, stream>>>(agg_col, h_col, c1_nc_WlT, c1_nc_bl, c1_nc_WrT, n_col, N_COL);

    // ---- conv2 con->col (col->con branch dead) + fused Q-head ----
    gather_mean_k<<<(N_COL + 3) / 4, 256, 0, stream>>>(n_con, srclist_col, offs_col, cnt_col, agg_col, N_COL);
    sage_gemm_q_k<<<(N_COL + 63) / 64, 256, 0, stream>>>(agg_col, n_col, c2_nc_WlT, c2_nc_bl, c2_nc_WrT,
                                                         q_W1T, q_b1, q_W2, q_b2, out, N_COL);
}